// Round 6
// baseline (518.302 us; speedup 1.0000x reference)
//
#include <hip/hip_runtime.h>
#include <math.h>

#define S_LEN 2048
#define DMODEL 2560
#define NH 32
#define NKV 8
#define HD 128
#define QDIM (NH*HD)     // 4096
#define KVDIM (NKV*HD)   // 1024
#define ROPE_THETA 5000000.0
#define QK_SCALE 0.08838834764831843f

typedef __attribute__((ext_vector_type(8))) short s16x8;
typedef __attribute__((ext_vector_type(4))) float f32x4;
typedef unsigned short u16;

#define MFMA16(a,b,c) __builtin_amdgcn_mfma_f32_16x16x32_bf16((a),(b),(c),0,0,0)

__device__ __forceinline__ u16 f2bf(float x) {
    union { float f; unsigned u; } v; v.f = x;
    unsigned r = v.u + 0x7FFFu + ((v.u >> 16) & 1u);
    return (u16)(r >> 16);
}
__device__ __forceinline__ float bf2f(u16 h) {
    union { unsigned u; float f; } v; v.u = ((unsigned)h) << 16;
    return v.f;
}

// Swizzled LDS index, CKU units of 8 bf16 per row; XOR low-3 bits of unit.
__device__ __forceinline__ int lsw(int row, int kb, int CKU) {
    return (((row * CKU + kb) ^ (row & 7)) << 3);
}
// K arrays: CKU=16, XOR all 4 unit bits (full 256B spread).
__device__ __forceinline__ int lswK(int row, int kb) {
    return ((row * 16 + (kb ^ (row & 15))) << 3);
}

// async global->LDS, 16B per lane; LDS dest = wave-uniform base + lane*16.
__device__ __forceinline__ void gload16(const void* g, void* l) {
    __builtin_amdgcn_global_load_lds(
        (const __attribute__((address_space(1))) void*)g,
        (__attribute__((address_space(3))) void*)l, 16, 0, 0);
}

// ---------------------------------------------------------------------------
// prep_all: all input-side elementwise work in ONE launch.
// ---------------------------------------------------------------------------
#define N4_X   (S_LEN*DMODEL/4)      // 1310720
#define N4_WQ  (QDIM*DMODEL/4)       // 2621440
#define N4_WKV (KVDIM*DMODEL/4)      // 655360
#define N4_WO  (DMODEL*QDIM/4)       // 2621440
#define N_TAB  (S_LEN*64)            // 131072
#define PREP_TOTAL (N4_X + N4_WQ + N4_WKV + N4_WKV + N4_WO + N_TAB)

__device__ __forceinline__ void split4(const float* in, long i,
                                       u16* hi, u16* lo) {
    float4 v = ((const float4*)in)[i];
    float a[4] = {v.x, v.y, v.z, v.w};
    u16 hh[4], ll[4];
    #pragma unroll
    for (int j = 0; j < 4; ++j) {
        hh[j] = f2bf(a[j]);
        ll[j] = f2bf(a[j] - bf2f(hh[j]));
    }
    ((uint2*)hi)[i] = make_uint2((unsigned)hh[0] | ((unsigned)hh[1] << 16),
                                 (unsigned)hh[2] | ((unsigned)hh[3] << 16));
    ((uint2*)lo)[i] = make_uint2((unsigned)ll[0] | ((unsigned)ll[1] << 16),
                                 (unsigned)ll[2] | ((unsigned)ll[3] << 16));
}
__device__ __forceinline__ void cvt4(const float* in, long i, u16* out) {
    float4 v = ((const float4*)in)[i];
    u16 h0 = f2bf(v.x), h1 = f2bf(v.y), h2 = f2bf(v.z), h3 = f2bf(v.w);
    ((uint2*)out)[i] = make_uint2((unsigned)h0 | ((unsigned)h1 << 16),
                                  (unsigned)h2 | ((unsigned)h3 << 16));
}

__global__ __launch_bounds__(256)
void prep_all(const float* __restrict__ x, const float* __restrict__ w_q,
              const float* __restrict__ w_k, const float* __restrict__ w_v,
              const float* __restrict__ w_o, const int* __restrict__ pos,
              u16* __restrict__ XH, u16* __restrict__ XL,
              u16* __restrict__ WQH, u16* __restrict__ WQL,
              u16* __restrict__ WKH, u16* __restrict__ WKL,
              u16* __restrict__ WVH, u16* __restrict__ WOH,
              float* __restrict__ cost, float* __restrict__ sint) {
    long i = (long)blockIdx.x * 256 + threadIdx.x;
    if (i < N4_X) { split4(x, i, XH, XL); return; }
    i -= N4_X;
    if (i < N4_WQ) { split4(w_q, i, WQH, WQL); return; }
    i -= N4_WQ;
    if (i < N4_WKV) { split4(w_k, i, WKH, WKL); return; }
    i -= N4_WKV;
    if (i < N4_WKV) { cvt4(w_v, i, WVH); return; }
    i -= N4_WKV;
    if (i < N4_WO) { cvt4(w_o, i, WOH); return; }
    i -= N4_WO;
    if (i < N_TAB) {
        int s = (int)(i >> 6), j = (int)(i & 63);
        double inv = pow((double)ROPE_THETA, -(double)j / 64.0);
        double ang = (double)pos[s] * inv;
        cost[i] = (float)cos(ang);
        sint[i] = (float)sin(ang);
    }
}

// ---------------------------------------------------------------------------
// merged rope: q (scaled, ws) + k (in-place fp32 cache) -> bf16 hi/lo splits
// ---------------------------------------------------------------------------
__global__ __launch_bounds__(256)
void rope_qk_split(float* __restrict__ q32, float* __restrict__ k,
                   const float* __restrict__ cost, const float* __restrict__ sint,
                   u16* __restrict__ qhh, u16* __restrict__ qll,
                   u16* __restrict__ khh, u16* __restrict__ kll) {
    int idx = blockIdx.x * 256 + threadIdx.x;
    if (idx < S_LEN * NH * 64) {
        int j = idx & 63;
        int h = (idx >> 6) & 31;
        int s = idx >> 11;
        float c = cost[(s << 6) + j], sn = sint[(s << 6) + j];
        size_t base = (size_t)s * QDIM + (size_t)h * HD;
        float x1 = q32[base + j], x2 = q32[base + 64 + j];
        float y1 = (x1 * c - x2 * sn) * QK_SCALE;
        float y2 = (x2 * c + x1 * sn) * QK_SCALE;
        u16 h1 = f2bf(y1), h2 = f2bf(y2);
        qhh[base + j] = h1;      qll[base + j] = f2bf(y1 - bf2f(h1));
        qhh[base + 64 + j] = h2; qll[base + 64 + j] = f2bf(y2 - bf2f(h2));
    } else {
        idx -= S_LEN * NH * 64;
        int j = idx & 63;
        int s = (idx >> 6) & 2047;
        int h = idx >> 17;
        float c = cost[(s << 6) + j], sn = sint[(s << 6) + j];
        size_t base = ((size_t)h * S_LEN + s) * HD;
        float x1 = k[base + j], x2 = k[base + 64 + j];
        float y1 = x1 * c - x2 * sn;
        float y2 = x2 * c + x1 * sn;
        k[base + j] = y1; k[base + 64 + j] = y2;
        u16 h1 = f2bf(y1), h2 = f2bf(y2);
        khh[base + j] = h1;      kll[base + j] = f2bf(y1 - bf2f(h1));
        khh[base + 64 + j] = h2; kll[base + 64 + j] = f2bf(y2 - bf2f(h2));
    }
}

// ---------------------------------------------------------------------------
// V^T builder: v [8][2048][128] fp32 -> vt [8][128][2048] bf16 (coalesced).
// ---------------------------------------------------------------------------
__global__ __launch_bounds__(256)
void vt_transpose(const float* __restrict__ v, u16* __restrict__ vt) {
    __shared__ u16 t[64][80];
    const int kvh = blockIdx.y;
    const int st = blockIdx.x >> 1, dt = blockIdx.x & 1;
    const int tid = threadIdx.x;
    const int r = tid & 15, c4 = (tid >> 4) * 4;
    const float* vb = v + ((size_t)kvh * S_LEN + st * 64) * HD + dt * 64;
    #pragma unroll
    for (int p = 0; p < 4; ++p) {
        int row = p * 16 + r;
        float4 x = *(const float4*)&vb[(size_t)row * HD + c4];
        t[c4 + 0][row] = f2bf(x.x);
        t[c4 + 1][row] = f2bf(x.y);
        t[c4 + 2][row] = f2bf(x.z);
        t[c4 + 3][row] = f2bf(x.w);
    }
    __syncthreads();
    #pragma unroll
    for (int p = 0; p < 2; ++p) {
        int idx = p * 256 + tid;
        int dr = idx >> 3, sc = idx & 7;
        size_t o = ((size_t)kvh * HD + dt * 64 + dr) * S_LEN + st * 64 + sc * 8;
        *(int4*)&vt[o] = *(const int4*)&t[dr][sc * 8];
    }
}

// ---------------------------------------------------------------------------
// Shared split-bf16 MFMA GEMM body (NT): 128x128 tile, BK=64.
// cmode 0: C row-major [M][N]. cmode 1: kv-cache layout [col>>7][row][col&127].
// ---------------------------------------------------------------------------
__device__ __forceinline__ void gemm_body(
    u16* lds, const u16* __restrict__ Ah, const u16* __restrict__ Al,
    const u16* __restrict__ Bh, const u16* __restrict__ Bl, bool full,
    float* __restrict__ C, int N, int K, int m0, int n0, int cmode) {
    u16* Ahs = lds;
    u16* Als = lds + 8192;
    u16* Bhs = lds + 16384;
    u16* Bls = lds + 24576;
    const int tid = threadIdx.x;
    const int lane = tid & 63, w = tid >> 6;
    const int q4 = lane >> 4, r15 = lane & 15;
    const int wm = (w >> 1) * 64, wn = (w & 1) * 64;

    f32x4 acc[4][4];
    #pragma unroll
    for (int i = 0; i < 4; ++i)
        #pragma unroll
        for (int j = 0; j < 4; ++j) acc[i][j] = (f32x4)(0.0f);

    for (int k0 = 0; k0 < K; k0 += 64) {
        __syncthreads();
        for (int ch = w; ch < 16; ch += 4) {
            int u = ch * 64 + lane;
            int row = u >> 3;
            int kb = (u & 7) ^ (row & 7);
            size_t goff = (size_t)row * K + k0 + kb * 8;
            gload16(Ah + (size_t)m0 * K + goff, &Ahs[ch * 512]);
            gload16(Bh + (size_t)n0 * K + goff, &Bhs[ch * 512]);
            if (full) {
                gload16(Al + (size_t)m0 * K + goff, &Als[ch * 512]);
                gload16(Bl + (size_t)n0 * K + goff, &Bls[ch * 512]);
            }
        }
        __syncthreads();   // drains vmcnt(0): LDS tiles ready

        #pragma unroll
        for (int kh2 = 0; kh2 < 2; ++kh2) {
            int kb = kh2 * 4 + q4;
            s16x8 ah[4], bh[4];
            #pragma unroll
            for (int i = 0; i < 4; ++i) ah[i] = *(const s16x8*)&Ahs[lsw(wm + i * 16 + r15, kb, 8)];
            #pragma unroll
            for (int j = 0; j < 4; ++j) bh[j] = *(const s16x8*)&Bhs[lsw(wn + j * 16 + r15, kb, 8)];
            if (full) {
                s16x8 al[4], bl2[4];
                #pragma unroll
                for (int i = 0; i < 4; ++i) al[i] = *(const s16x8*)&Als[lsw(wm + i * 16 + r15, kb, 8)];
                #pragma unroll
                for (int j = 0; j < 4; ++j) bl2[j] = *(const s16x8*)&Bls[lsw(wn + j * 16 + r15, kb, 8)];
                #pragma unroll
                for (int i = 0; i < 4; ++i)
                    #pragma unroll
                    for (int j = 0; j < 4; ++j) {
                        acc[i][j] = MFMA16(ah[i], bh[j], acc[i][j]);
                        acc[i][j] = MFMA16(ah[i], bl2[j], acc[i][j]);
                        acc[i][j] = MFMA16(al[i], bh[j], acc[i][j]);
                    }
            } else {
                #pragma unroll
                for (int i = 0; i < 4; ++i)
                    #pragma unroll
                    for (int j = 0; j < 4; ++j)
                        acc[i][j] = MFMA16(ah[i], bh[j], acc[i][j]);
            }
        }
    }

    // epilogue: D layout col = lane&15, row = (lane>>4)*4 + r
    #pragma unroll
    for (int i = 0; i < 4; ++i) {
        #pragma unroll
        for (int j = 0; j < 4; ++j) {
            int col = n0 + wn + j * 16 + r15;
            #pragma unroll
            for (int r = 0; r < 4; ++r) {
                int row = m0 + wm + i * 16 + q4 * 4 + r;
                float val = acc[i][j][r];
                if (cmode == 0)
                    C[(size_t)row * N + col] = val;
                else
                    C[((size_t)(col >> 7) * S_LEN + row) * HD + (col & 127)] = val;
            }
        }
    }
}

// fused Q/K/V projection: grid (48, 16)
__global__ __launch_bounds__(256, 2)
void gemm_qkv(const u16* __restrict__ XH, const u16* __restrict__ XL,
              const u16* __restrict__ WQH, const u16* __restrict__ WQL,
              const u16* __restrict__ WKH, const u16* __restrict__ WKL,
              const u16* __restrict__ WVH,
              float* __restrict__ Q32, float* __restrict__ out_k,
              float* __restrict__ out_v) {
    __shared__ u16 lds[32768];
    const int bx = blockIdx.x, m0 = blockIdx.y * 128;
    if (bx < 32)
        gemm_body(lds, XH, XL, WQH, WQL, true, Q32, QDIM, DMODEL, m0, bx * 128, 0);
    else if (bx < 40)
        gemm_body(lds, XH, XL, WKH, WKL, true, out_k, KVDIM, DMODEL, m0, (bx - 32) * 128, 1);
    else
        gemm_body(lds, XH, XL, WVH, WVH, false, out_v, KVDIM, DMODEL, m0, (bx - 40) * 128, 1);
}

// O projection (plain bf16): grid (20, 16)
__global__ __launch_bounds__(256, 2)
void gemm_o(const u16* __restrict__ AOH, const u16* __restrict__ WOH,
            float* __restrict__ out) {
    __shared__ u16 lds[32768];
    gemm_body(lds, AOH, AOH, WOH, WOH, false, out, DMODEL, QDIM,
              blockIdx.y * 128, blockIdx.x * 128, 0);
}

// ---------------------------------------------------------------------------
// MFMA flash attention v5. 512 thr = 8 waves; 2 heads x 2 causally-paired
// q-tiles (33 computes/block). Grid 256 (1 block/CU, LDS-forced). Double-
// buffered K/V via global_load_lds. B/V fragments shared across q-tiles.
// waves_per_eu(2,2): LDS already caps at 2 waves/EU, so take the full
// 256-VGPR budget -> no spills (round-5 lesson: 128-cap spilled ~60 regs).
// ---------------------------------------------------------------------------
__global__ __attribute__((amdgpu_flat_work_group_size(512, 512)))
__attribute__((amdgpu_waves_per_eu(2, 2)))
void attn_mfma5(const u16* __restrict__ qh, const u16* __restrict__ ql,
                const u16* __restrict__ kh, const u16* __restrict__ kl,
                const u16* __restrict__ vt, u16* __restrict__ aoh) {
    const int bid = blockIdx.x;
    const int kvh = bid & 7;               // XCD-pinned under round-robin
    const int rest = bid >> 3;
    const int hp = rest & 1;
    const int qpair = rest >> 1;           // 0..15
    const int qtA = qpair, qtB = 31 - qpair;
    const int KTB = qtB + 1;

    const int tid = threadIdx.x, lane = tid & 63, w = tid >> 6;
    const int lh = w >> 2, wq = w & 3;
    const int head = kvh * 4 + hp * 2 + lh;
    const int q4 = lane >> 4, r15 = lane & 15;

    __shared__ u16 Khs[2][64 * 128], Kls[2][64 * 128];   // 32KB + 32KB
    __shared__ u16 Vts[2][128 * 64];                     // 32KB
    __shared__ u16 Ps[2][64 * 64];                       // 16KB
    u16* Psh = Ps[lh];

    // Q fragments (both q-tiles) in registers
    s16x8 qfh[2][4], qfl[2][4];
    #pragma unroll
    for (int t = 0; t < 2; ++t) {
        int qt = t ? qtB : qtA;
        size_t qrow = (size_t)qt * 64 + wq * 16 + r15;
        const u16* qb  = qh + qrow * QDIM + (size_t)head * HD + q4 * 8;
        const u16* qb2 = ql + qrow * QDIM + (size_t)head * HD + q4 * 8;
        #pragma unroll
        for (int db = 0; db < 4; ++db) {
            qfh[t][db] = *(const s16x8*)(qb + db * 32);
            qfl[t][db] = *(const s16x8*)(qb2 + db * 32);
        }
    }

    f32x4 acco[2][8];
    float mrow[2][4], lrow[2][4];
    #pragma unroll
    for (int t = 0; t < 2; ++t) {
        #pragma unroll
        for (int db = 0; db < 8; ++db) acco[t][db] = (f32x4)(0.0f);
        #pragma unroll
        for (int r = 0; r < 4; ++r) { mrow[t][r] = -1e30f; lrow[t][r] = 0.f; }
    }

    const u16* kbase = kh + (size_t)kvh * S_LEN * HD;
    const u16* lbase = kl + (size_t)kvh * S_LEN * HD;
    const u16* vbase = vt + (size_t)kvh * HD * S_LEN;

    auto stage = [&](int kt, int buf) {
        for (int c = w; c < 48; c += 8) {
            int c15 = c & 15;
            int u = c15 * 64 + lane;
            if (c < 32) {
                int krow = u >> 4;
                int kb = (u & 15) ^ (krow & 15);       // 4-bit pre-swizzle
                size_t g = (size_t)(kt * 64 + krow) * HD + kb * 8;
                const u16* src = (c < 16 ? kbase : lbase) + g;
                u16* dst = (c < 16 ? &Khs[buf][c15 * 512] : &Kls[buf][c15 * 512]);
                gload16(src, dst);
            } else {
                int vrow = u >> 3;
                int vb2 = (u & 7) ^ (vrow & 7);
                gload16(vbase + (size_t)vrow * S_LEN + kt * 64 + vb2 * 8,
                        &Vts[buf][c15 * 512]);
            }
        }
    };

    stage(0, 0);
    __syncthreads();   // vmcnt(0) drained

    for (int kt = 0; kt < KTB; ++kt) {
        const int cur = kt & 1;
        if (kt + 1 < KTB) stage(kt + 1, cur ^ 1);   // async prefetch
        const bool act0 = (kt <= qtA);

        // ---- QK^T; shared B-fragments when both tiles active ----
        f32x4 sf[2][4];
        #pragma unroll
        for (int kf = 0; kf < 4; ++kf) { sf[0][kf] = (f32x4)(0.0f); sf[1][kf] = (f32x4)(0.0f); }
        if (act0) {
            #pragma unroll
            for (int db = 0; db < 4; ++db) {
                int kb = db * 4 + q4;
                #pragma unroll
                for (int kf = 0; kf < 4; ++kf) {
                    s16x8 bh  = *(const s16x8*)&Khs[cur][lswK(kf * 16 + r15, kb)];
                    s16x8 bl2 = *(const s16x8*)&Kls[cur][lswK(kf * 16 + r15, kb)];
                    sf[1][kf] = MFMA16(qfh[1][db], bh, sf[1][kf]);
                    sf[1][kf] = MFMA16(qfh[1][db], bl2, sf[1][kf]);
                    sf[1][kf] = MFMA16(qfl[1][db], bh, sf[1][kf]);
                    sf[0][kf] = MFMA16(qfh[0][db], bh, sf[0][kf]);
                    sf[0][kf] = MFMA16(qfh[0][db], bl2, sf[0][kf]);
                    sf[0][kf] = MFMA16(qfl[0][db], bh, sf[0][kf]);
                }
            }
        } else {
            #pragma unroll
            for (int db = 0; db < 4; ++db) {
                int kb = db * 4 + q4;
                #pragma unroll
                for (int kf = 0; kf < 4; ++kf) {
                    s16x8 bh  = *(const s16x8*)&Khs[cur][lswK(kf * 16 + r15, kb)];
                    s16x8 bl2 = *(const s16x8*)&Kls[cur][lswK(kf * 16 + r15, kb)];
                    sf[1][kf] = MFMA16(qfh[1][db], bh, sf[1][kf]);
                    sf[1][kf] = MFMA16(qfh[1][db], bl2, sf[1][kf]);
                    sf[1][kf] = MFMA16(qfl[1][db], bh, sf[1][kf]);
                }
            }
        }

        // ---- per-tile softmax + P write + P-fragment pickup ----
        s16x8 pa[2][2];
        #pragma unroll
        for (int t = 0; t < 2; ++t) {
            if (t == 0 && !act0) continue;
            const int qt = t ? qtB : qtA;

            if (kt == qt) {   // diagonal mask
                #pragma unroll
                for (int kf = 0; kf < 4; ++kf) {
                    int col = kf * 16 + r15;
                    #pragma unroll
                    for (int r = 0; r < 4; ++r) {
                        int rowg = wq * 16 + q4 * 4 + r;
                        if (col > rowg) sf[t][kf][r] = -1e30f;
                    }
                }
            }

            float pmax[4];
            #pragma unroll
            for (int r = 0; r < 4; ++r)
                pmax[r] = fmaxf(fmaxf(sf[t][0][r], sf[t][1][r]), fmaxf(sf[t][2][r], sf[t][3][r]));
            #pragma unroll
            for (int o = 1; o < 16; o <<= 1)
                #pragma unroll
                for (int r = 0; r < 4; ++r)
                    pmax[r] = fmaxf(pmax[r], __shfl_xor(pmax[r], o));

            float dmax = fmaxf(fmaxf(pmax[0] - mrow[t][0], pmax[1] - mrow[t][1]),
                               fmaxf(pmax[2] - mrow[t][2], pmax[3] - mrow[t][3]));
            if (!__all(dmax <= 8.0f)) {
                #pragma unroll
                for (int r = 0; r < 4; ++r) {
                    float mn = fmaxf(mrow[t][r], pmax[r]);
                    float corr = __expf(mrow[t][r] - mn);
                    mrow[t][r] = mn;
                    lrow[t][r] *= corr;
                    #pragma unroll
                    for (int db = 0; db < 8; ++db) acco[t][db][r] *= corr;
                }
            }

            float rs[4];
            #pragma unroll
            for (int r = 0; r < 4; ++r) {
                float s0 = __expf(sf[t][0][r] - mrow[t][r]);
                float s1 = __expf(sf[t][1][r] - mrow[t][r]);
                float s2 = __expf(sf[t][2][r] - mrow[t][r]);
                float s3 = __expf(sf[t][3][r] - mrow[t][r]);
                sf[t][0][r] = s0; sf[t][1][r] = s1; sf[t][2][r] = s2; sf[t][3][r] = s3;
                rs[r] = (s0 + s1) + (s2 + s3);
            }
            #pragma unroll
            for (int o = 1; o < 16; o <<= 1)
                #pragma unroll
                for (int r = 0; r < 4; ++r)
                    rs[r] += __shfl_xor(rs[r], o);
            #pragma unroll
            for (int r = 0; r < 4; ++r) lrow[t][r] += rs[r];

            #pragma unroll
            for (int kf = 0; kf < 4; ++kf) {
                int col = kf * 16 + r15;
                #pragma unroll
                for (int r = 0; r < 4; ++r) {
                    int prow = wq * 16 + q4 * 4 + r;
                    Psh[lsw(prow, col >> 3, 8) + (col & 7)] = f2bf(sf[t][kf][r]);
                }
            }
            // same-wave RAW: pick up this tile's P fragments into registers
            pa[t][0] = *(const s16x8*)&Psh[lsw(wq * 16 + r15, q4, 8)];
            pa[t][1] = *(const s16x8*)&Psh[lsw(wq * 16 + r15, 4 + q4, 8)];
        }

        // ---- PV; shared V-fragments when both tiles active ----
        if (act0) {
            #pragma unroll
            for (int db = 0; db < 8; ++db) {
                s16x8 vb0 = *(const s16x8*)&Vts[cur][lsw(db * 16 + r15, q4, 8)];
                s16x8 vb1 = *(const s16x8*)&Vts[cur][lsw(db * 16 + r15, 4 + q4, 8)];
                acco[1][db] = MFMA16(pa[1][0], vb0, acco[1][db]);
                acco[1][db] = MFMA16(pa[1][1], vb1, acco[1][db]);
                acco[0][db] = MFMA16(pa[0][0], vb0, acco[0][db]);
                acco[0][db] = MFMA16(pa[0][1], vb1, acco[0][db]);
            }
        } else {
            #pragma unroll
            for (int db = 0; db < 8; ++db) {
                s16x8 vb0 = *(const s16x8*)&Vts[cur][lsw(db * 16 + r15, q4, 8)];
                s16x8 vb1 = *(const s16x8*)&Vts[cur][lsw(db * 16 + r15, 4 + q4, 8)];
                acco[1][db] = MFMA16(pa[1][0], vb0, acco[1][db]);
                acco[1][db] = MFMA16(pa[1][1], vb1, acco[1][db]);
            }
        }

        __syncthreads();  // next tile staged; all waves done with cur
    }

    // epilogue: normalize, pack bf16 rows in LDS scratch, coalesced store
    u16* scr = ((u16*)Khs) + w * 2048;    // 4KB private per wave
    #pragma unroll
    for (int t = 0; t < 2; ++t) {
        const int qt = t ? qtB : qtA;
        float inv[4];
        #pragma unroll
        for (int r = 0; r < 4; ++r) inv[r] = 1.0f / lrow[t][r];
        #pragma unroll
        for (int db = 0; db < 8; ++db)
            #pragma unroll
            for (int r = 0; r < 4; ++r)
                scr[(q4 * 4 + r) * 128 + db * 16 + r15] = f2bf(acco[t][db][r] * inv[r]);
        #pragma unroll
        for (int p = 0; p < 4; ++p) {
            int idx = p * 512 + lane * 8;
            int lr = idx >> 7, col = idx & 127;
            size_t grow = (size_t)qt * 64 + wq * 16 + lr;
            *(int4*)&aoh[grow * QDIM + (size_t)head * HD + col] = *(const int4*)&scr[idx];
        }
    }
}

// ---------------------------------------------------------------------------
extern "C" void kernel_launch(void* const* d_in, const int* in_sizes, int n_in,
                              void* d_out, int out_size, void* d_ws, size_t ws_size,
                              hipStream_t stream) {
    const float* x   = (const float*)d_in[0];
    const int*   pos = (const int*)d_in[1];
    const float* w_q = (const float*)d_in[2];
    const float* w_k = (const float*)d_in[3];
    const float* w_v = (const float*)d_in[4];
    const float* w_o = (const float*)d_in[5];

    float* out   = (float*)d_out;
    float* out_k = out + (size_t)S_LEN * DMODEL;
    float* out_v = out_k + (size_t)NKV * S_LEN * HD;

    // ---- workspace arena ----
    char* ws = (char*)d_ws;
    size_t off = 0;
    auto alloc = [&](size_t bytes) { char* p = ws + off; off += (bytes + 255) & ~255ull; return p; };
    float* cost = (float*)alloc((size_t)S_LEN * 64 * 4);
    float* sint = (float*)alloc((size_t)S_LEN * 64 * 4);
    float* Q32  = (float*)alloc((size_t)S_LEN * QDIM * 4);      // later: AOH (bf16)
    u16* XH  = (u16*)alloc((size_t)S_LEN * DMODEL * 2);         // later: KH
    u16* XL  = (u16*)alloc((size_t)S_LEN * DMODEL * 2);         // later: KL
    u16* WQH = (u16*)alloc((size_t)QDIM * DMODEL * 2);
    u16* WQL = (u16*)alloc((size_t)QDIM * DMODEL * 2);          // later: QH
    u16* WKH = (u16*)alloc((size_t)KVDIM * DMODEL * 2);
    u16* WKL = (u16*)alloc((size_t)KVDIM * DMODEL * 2);
    u16* WVH = (u16*)alloc((size_t)KVDIM * DMODEL * 2);
    u16* WOH = (u16*)alloc((size_t)DMODEL * QDIM * 2);
    u16* QL  = (u16*)alloc((size_t)S_LEN * QDIM * 2);
    u16* VT  = (u16*)alloc((size_t)NKV * HD * S_LEN * 2);
    u16* AOH = (u16*)Q32;     // alias: Q32 dead after rope_qk_split
    u16* KH  = XH;            // alias: XH dead after gemm_qkv
    u16* KL  = XL;
    u16* QH  = WQL;           // alias: WQL dead after gemm_qkv

    // 1. all input prep (splits + rope tables) in one launch
    prep_all<<<PREP_TOTAL / 256, 256, 0, stream>>>(
        x, w_q, w_k, w_v, w_o, pos, XH, XL, WQH, WQL, WKH, WKL, WVH, WOH, cost, sint);

    // 2. fused Q/K/V projections
    gemm_qkv<<<dim3(48, 16), 256, 0, stream>>>(
        XH, XL, WQH, WQL, WKH, WKL, WVH, Q32, out_k, out_v);

    // 3. V^T + fused rope/scale/split for q and k
    vt_transpose<<<dim3(64, 8), 256, 0, stream>>>(out_v, VT);
    rope_qk_split<<<(S_LEN * (NH + NKV) * 64) / 256, 256, 0, stream>>>(
        Q32, out_k, cost, sint, QH, QL, KH, KL);

    // 4. attention -> bf16 AO
    attn_mfma5<<<256, 512, 0, stream>>>(QH, QL, KH, KL, VT, AOH);

    // 5. O projection (plain bf16)
    gemm_o<<<dim3(DMODEL / 128, 16), 256, 0, stream>>>(AOH, WOH, out);
}

// Round 7
// 485.731 us; speedup vs baseline: 1.0671x; 1.0671x over previous
//
#include <hip/hip_runtime.h>
#include <math.h>

#define S_LEN 2048
#define DMODEL 2560
#define NH 32
#define NKV 8
#define HD 128
#define QDIM (NH*HD)     // 4096
#define KVDIM (NKV*HD)   // 1024
#define ROPE_THETA 5000000.0
#define QK_SCALE 0.08838834764831843f

typedef __attribute__((ext_vector_type(8))) short s16x8;
typedef __attribute__((ext_vector_type(4))) float f32x4;
typedef unsigned short u16;

#define MFMA16(a,b,c) __builtin_amdgcn_mfma_f32_16x16x32_bf16((a),(b),(c),0,0,0)

__device__ __forceinline__ u16 f2bf(float x) {
    union { float f; unsigned u; } v; v.f = x;
    unsigned r = v.u + 0x7FFFu + ((v.u >> 16) & 1u);
    return (u16)(r >> 16);
}
__device__ __forceinline__ float bf2f(u16 h) {
    union { unsigned u; float f; } v; v.u = ((unsigned)h) << 16;
    return v.f;
}

// Swizzled LDS index, CKU units of 8 bf16 per row; XOR low-3 bits of unit.
__device__ __forceinline__ int lsw(int row, int kb, int CKU) {
    return (((row * CKU + kb) ^ (row & 7)) << 3);
}
// K arrays: CKU=16, XOR all 4 unit bits (full 256B spread).
__device__ __forceinline__ int lswK(int row, int kb) {
    return ((row * 16 + (kb ^ (row & 15))) << 3);
}

// async global->LDS, 16B per lane; LDS dest = wave-uniform base + lane*16.
__device__ __forceinline__ void gload16(const void* g, void* l) {
    __builtin_amdgcn_global_load_lds(
        (const __attribute__((address_space(1))) void*)g,
        (__attribute__((address_space(3))) void*)l, 16, 0, 0);
}

// ---------------------------------------------------------------------------
// prep_all: all input-side elementwise work in ONE launch.
// ---------------------------------------------------------------------------
#define N4_X   (S_LEN*DMODEL/4)      // 1310720
#define N4_WQ  (QDIM*DMODEL/4)       // 2621440
#define N4_WKV (KVDIM*DMODEL/4)      // 655360
#define N4_WO  (DMODEL*QDIM/4)       // 2621440
#define N_TAB  (S_LEN*64)            // 131072
#define PREP_TOTAL (N4_X + N4_WQ + N4_WKV + N4_WKV + N4_WO + N_TAB)

__device__ __forceinline__ void split4(const float* in, long i,
                                       u16* hi, u16* lo) {
    float4 v = ((const float4*)in)[i];
    float a[4] = {v.x, v.y, v.z, v.w};
    u16 hh[4], ll[4];
    #pragma unroll
    for (int j = 0; j < 4; ++j) {
        hh[j] = f2bf(a[j]);
        ll[j] = f2bf(a[j] - bf2f(hh[j]));
    }
    ((uint2*)hi)[i] = make_uint2((unsigned)hh[0] | ((unsigned)hh[1] << 16),
                                 (unsigned)hh[2] | ((unsigned)hh[3] << 16));
    ((uint2*)lo)[i] = make_uint2((unsigned)ll[0] | ((unsigned)ll[1] << 16),
                                 (unsigned)ll[2] | ((unsigned)ll[3] << 16));
}
__device__ __forceinline__ void cvt4(const float* in, long i, u16* out) {
    float4 v = ((const float4*)in)[i];
    u16 h0 = f2bf(v.x), h1 = f2bf(v.y), h2 = f2bf(v.z), h3 = f2bf(v.w);
    ((uint2*)out)[i] = make_uint2((unsigned)h0 | ((unsigned)h1 << 16),
                                  (unsigned)h2 | ((unsigned)h3 << 16));
}

__global__ __launch_bounds__(256)
void prep_all(const float* __restrict__ x, const float* __restrict__ w_q,
              const float* __restrict__ w_k, const float* __restrict__ w_v,
              const float* __restrict__ w_o, const int* __restrict__ pos,
              u16* __restrict__ XH, u16* __restrict__ XL,
              u16* __restrict__ WQH, u16* __restrict__ WQL,
              u16* __restrict__ WKH, u16* __restrict__ WKL,
              u16* __restrict__ WVH, u16* __restrict__ WOH,
              float* __restrict__ cost, float* __restrict__ sint) {
    long i = (long)blockIdx.x * 256 + threadIdx.x;
    if (i < N4_X) { split4(x, i, XH, XL); return; }
    i -= N4_X;
    if (i < N4_WQ) { split4(w_q, i, WQH, WQL); return; }
    i -= N4_WQ;
    if (i < N4_WKV) { split4(w_k, i, WKH, WKL); return; }
    i -= N4_WKV;
    if (i < N4_WKV) { cvt4(w_v, i, WVH); return; }
    i -= N4_WKV;
    if (i < N4_WO) { cvt4(w_o, i, WOH); return; }
    i -= N4_WO;
    if (i < N_TAB) {
        int s = (int)(i >> 6), j = (int)(i & 63);
        double inv = pow((double)ROPE_THETA, -(double)j / 64.0);
        double ang = (double)pos[s] * inv;
        cost[i] = (float)cos(ang);
        sint[i] = (float)sin(ang);
    }
}

// ---------------------------------------------------------------------------
// merged rope: q (scaled, ws) + k (in-place fp32 cache) -> bf16 hi/lo splits
// ---------------------------------------------------------------------------
__global__ __launch_bounds__(256)
void rope_qk_split(float* __restrict__ q32, float* __restrict__ k,
                   const float* __restrict__ cost, const float* __restrict__ sint,
                   u16* __restrict__ qhh, u16* __restrict__ qll,
                   u16* __restrict__ khh, u16* __restrict__ kll) {
    int idx = blockIdx.x * 256 + threadIdx.x;
    if (idx < S_LEN * NH * 64) {
        int j = idx & 63;
        int h = (idx >> 6) & 31;
        int s = idx >> 11;
        float c = cost[(s << 6) + j], sn = sint[(s << 6) + j];
        size_t base = (size_t)s * QDIM + (size_t)h * HD;
        float x1 = q32[base + j], x2 = q32[base + 64 + j];
        float y1 = (x1 * c - x2 * sn) * QK_SCALE;
        float y2 = (x2 * c + x1 * sn) * QK_SCALE;
        u16 h1 = f2bf(y1), h2 = f2bf(y2);
        qhh[base + j] = h1;      qll[base + j] = f2bf(y1 - bf2f(h1));
        qhh[base + 64 + j] = h2; qll[base + 64 + j] = f2bf(y2 - bf2f(h2));
    } else {
        idx -= S_LEN * NH * 64;
        int j = idx & 63;
        int s = (idx >> 6) & 2047;
        int h = idx >> 17;
        float c = cost[(s << 6) + j], sn = sint[(s << 6) + j];
        size_t base = ((size_t)h * S_LEN + s) * HD;
        float x1 = k[base + j], x2 = k[base + 64 + j];
        float y1 = x1 * c - x2 * sn;
        float y2 = x2 * c + x1 * sn;
        k[base + j] = y1; k[base + 64 + j] = y2;
        u16 h1 = f2bf(y1), h2 = f2bf(y2);
        khh[base + j] = h1;      kll[base + j] = f2bf(y1 - bf2f(h1));
        khh[base + 64 + j] = h2; kll[base + 64 + j] = f2bf(y2 - bf2f(h2));
    }
}

// ---------------------------------------------------------------------------
// V^T builder: v [8][2048][128] fp32 -> vt [8][128][2048] bf16 (coalesced).
// ---------------------------------------------------------------------------
__global__ __launch_bounds__(256)
void vt_transpose(const float* __restrict__ v, u16* __restrict__ vt) {
    __shared__ u16 t[64][80];
    const int kvh = blockIdx.y;
    const int st = blockIdx.x >> 1, dt = blockIdx.x & 1;
    const int tid = threadIdx.x;
    const int r = tid & 15, c4 = (tid >> 4) * 4;
    const float* vb = v + ((size_t)kvh * S_LEN + st * 64) * HD + dt * 64;
    #pragma unroll
    for (int p = 0; p < 4; ++p) {
        int row = p * 16 + r;
        float4 x = *(const float4*)&vb[(size_t)row * HD + c4];
        t[c4 + 0][row] = f2bf(x.x);
        t[c4 + 1][row] = f2bf(x.y);
        t[c4 + 2][row] = f2bf(x.z);
        t[c4 + 3][row] = f2bf(x.w);
    }
    __syncthreads();
    #pragma unroll
    for (int p = 0; p < 2; ++p) {
        int idx = p * 256 + tid;
        int dr = idx >> 3, sc = idx & 7;
        size_t o = ((size_t)kvh * HD + dt * 64 + dr) * S_LEN + st * 64 + sc * 8;
        *(int4*)&vt[o] = *(const int4*)&t[dr][sc * 8];
    }
}

// ---------------------------------------------------------------------------
// Segmented plain-bf16 MFMA GEMM (NT): C[m][n] = sum over nseg segments of
// A_si[m][0:Kb] . B_si[n][0:Kb].  Split-3 fp32 emulation = nseg 3 with
// A segs [XH,XH,XL], B segs [BH,BL,BH] -- plain GEMM inner loop, 32KB LDS,
// ~4 blocks/CU (the m97 ~900TF regime).
// cmode 0: C row-major [M][N]. cmode 1: kv-cache layout [col>>7][row][col&127].
// ---------------------------------------------------------------------------
__device__ __forceinline__ void gemm_seg_body(
    u16* lds, const u16* __restrict__ a0, const u16* __restrict__ a1,
    const u16* __restrict__ a2, const u16* __restrict__ b0,
    const u16* __restrict__ b1, const u16* __restrict__ b2,
    float* __restrict__ C, int N, int Kb, int nseg, int m0, int n0, int cmode) {
    u16* As = lds;
    u16* Bs = lds + 8192;
    const int tid = threadIdx.x;
    const int lane = tid & 63, w = tid >> 6;
    const int q4 = lane >> 4, r15 = lane & 15;
    const int wm = (w >> 1) * 64, wn = (w & 1) * 64;

    f32x4 acc[4][4];
    #pragma unroll
    for (int i = 0; i < 4; ++i)
        #pragma unroll
        for (int j = 0; j < 4; ++j) acc[i][j] = (f32x4)(0.0f);

    const int KT = nseg * Kb;
    for (int k0 = 0; k0 < KT; k0 += 64) {
        const int si = (k0 >= 2 * Kb) ? 2 : ((k0 >= Kb) ? 1 : 0);
        const int koff = k0 - si * Kb;
        const u16* Ag = (si == 0) ? a0 : ((si == 1) ? a1 : a2);
        const u16* Bg = (si == 0) ? b0 : ((si == 1) ? b1 : b2);
        __syncthreads();
        for (int ch = w; ch < 16; ch += 4) {
            int u = ch * 64 + lane;
            int row = u >> 3;
            int kb = (u & 7) ^ (row & 7);
            size_t go = (size_t)row * Kb + koff + kb * 8;
            gload16(Ag + (size_t)m0 * Kb + go, &As[ch * 512]);
            gload16(Bg + (size_t)n0 * Kb + go, &Bs[ch * 512]);
        }
        __syncthreads();   // drains vmcnt(0): LDS tiles ready

        #pragma unroll
        for (int kh2 = 0; kh2 < 2; ++kh2) {
            int kb = kh2 * 4 + q4;
            s16x8 ah[4], bh[4];
            #pragma unroll
            for (int i = 0; i < 4; ++i) ah[i] = *(const s16x8*)&As[lsw(wm + i * 16 + r15, kb, 8)];
            #pragma unroll
            for (int j = 0; j < 4; ++j) bh[j] = *(const s16x8*)&Bs[lsw(wn + j * 16 + r15, kb, 8)];
            #pragma unroll
            for (int i = 0; i < 4; ++i)
                #pragma unroll
                for (int j = 0; j < 4; ++j)
                    acc[i][j] = MFMA16(ah[i], bh[j], acc[i][j]);
        }
    }

    // epilogue: D layout col = lane&15, row = (lane>>4)*4 + r
    #pragma unroll
    for (int i = 0; i < 4; ++i) {
        #pragma unroll
        for (int j = 0; j < 4; ++j) {
            int col = n0 + wn + j * 16 + r15;
            #pragma unroll
            for (int r = 0; r < 4; ++r) {
                int row = m0 + wm + i * 16 + q4 * 4 + r;
                float val = acc[i][j][r];
                if (cmode == 0)
                    C[(size_t)row * N + col] = val;
                else
                    C[((size_t)(col >> 7) * S_LEN + row) * HD + (col & 127)] = val;
            }
        }
    }
}

// fused Q/K/V projection: grid (48, 16)
__global__ __launch_bounds__(256)
void gemm_qkv2(const u16* __restrict__ XH, const u16* __restrict__ XL,
               const u16* __restrict__ WQH, const u16* __restrict__ WQL,
               const u16* __restrict__ WKH, const u16* __restrict__ WKL,
               const u16* __restrict__ WVH,
               float* __restrict__ Q32, float* __restrict__ out_k,
               float* __restrict__ out_v) {
    __shared__ u16 lds[16384];
    const int bx = blockIdx.x, m0 = blockIdx.y * 128;
    if (bx < 32)        // Q: xh.wqh + xh.wql + xl.wqh
        gemm_seg_body(lds, XH, XH, XL, WQH, WQL, WQH, Q32, QDIM, DMODEL, 3, m0, bx * 128, 0);
    else if (bx < 40)   // K: split-3
        gemm_seg_body(lds, XH, XH, XL, WKH, WKL, WKH, out_k, KVDIM, DMODEL, 3, m0, (bx - 32) * 128, 1);
    else                // V: single-term
        gemm_seg_body(lds, XH, XH, XL, WVH, WVH, WVH, out_v, KVDIM, DMODEL, 1, m0, (bx - 40) * 128, 1);
}

// O projection (plain bf16): grid (20, 16)
__global__ __launch_bounds__(256)
void gemm_o2(const u16* __restrict__ AOH, const u16* __restrict__ WOH,
             float* __restrict__ out) {
    __shared__ u16 lds[16384];
    gemm_seg_body(lds, AOH, AOH, AOH, WOH, WOH, WOH, out, DMODEL, QDIM, 1,
                  blockIdx.y * 128, blockIdx.x * 128, 0);
}

// ---------------------------------------------------------------------------
// MFMA flash attention v6. 512 thr = 8 waves = 2 heads x 4 waves, ONE q-tile
// per block (low register state: qf 32 + acco 32 regs -> no spills).
// Grid 512: bid&7 = kvh (XCD-pinned); qt = idx<16 ? idx : 47-idx so the two
// blocks co-resident on a CU (bid, bid+256) have qt summing to 31 -> balanced.
// Single-buffered K/V (64KB LDS -> 2 blocks/CU); co-resident block's compute
// hides the stage-drain stall (TLP instead of dbuf).
// ---------------------------------------------------------------------------
__global__ __launch_bounds__(512, 4)
void attn_mfma6(const u16* __restrict__ qh, const u16* __restrict__ ql,
                const u16* __restrict__ kh, const u16* __restrict__ kl,
                const u16* __restrict__ vt, u16* __restrict__ aoh) {
    const int bid = blockIdx.x;
    const int kvh = bid & 7;
    const int rest = bid >> 3;             // 0..63
    const int hp = rest & 1;
    const int idx = rest >> 1;             // 0..31
    const int qt = (idx < 16) ? idx : 47 - idx;

    const int tid = threadIdx.x, lane = tid & 63, w = tid >> 6;
    const int lh = w >> 2, wq = w & 3;
    const int head = kvh * 4 + hp * 2 + lh;
    const int q4 = lane >> 4, r15 = lane & 15;

    __shared__ u16 Klds[2][64 * 128];      // [hi/lo][64][128] swizzled: 32KB
    __shared__ u16 Vts[128 * 64];          // [128][64] swizzled: 16KB
    __shared__ u16 Ps[2][64 * 64];         // per head-half: 16KB
    u16* Psh = Ps[lh];

    // Q fragments in registers (A-layout: row=r15, k = db*32 + q4*8 + jj)
    s16x8 qfh[4], qfl[4];
    {
        size_t qrow = (size_t)qt * 64 + wq * 16 + r15;
        const u16* qb  = qh + qrow * QDIM + (size_t)head * HD + q4 * 8;
        const u16* qb2 = ql + qrow * QDIM + (size_t)head * HD + q4 * 8;
        #pragma unroll
        for (int db = 0; db < 4; ++db) {
            qfh[db] = *(const s16x8*)(qb + db * 32);
            qfl[db] = *(const s16x8*)(qb2 + db * 32);
        }
    }

    f32x4 acco[8];
    #pragma unroll
    for (int db = 0; db < 8; ++db) acco[db] = (f32x4)(0.0f);
    float mrow[4] = {-1e30f, -1e30f, -1e30f, -1e30f};
    float lrow[4] = {0.f, 0.f, 0.f, 0.f};

    const u16* kbase = kh + (size_t)kvh * S_LEN * HD;
    const u16* lbase = kl + (size_t)kvh * S_LEN * HD;
    const u16* vbase = vt + (size_t)kvh * HD * S_LEN;

    for (int kt = 0; kt <= qt; ++kt) {
        // stage K hi/lo [64][128] + V^T [128][64] (pre-swizzled source)
        for (int c = w; c < 48; c += 8) {
            int c15 = c & 15;
            int u = c15 * 64 + lane;
            if (c < 32) {
                int krow = u >> 4;
                int kb = (u & 15) ^ (krow & 15);
                size_t g = (size_t)(kt * 64 + krow) * HD + kb * 8;
                const u16* src = (c < 16 ? kbase : lbase) + g;
                u16* dst = (c < 16 ? &Klds[0][c15 * 512] : &Klds[1][c15 * 512]);
                gload16(src, dst);
            } else {
                int vrow = u >> 3;
                int vb2 = (u & 7) ^ (vrow & 7);
                gload16(vbase + (size_t)vrow * S_LEN + kt * 64 + vb2 * 8,
                        &Vts[c15 * 512]);
            }
        }
        __syncthreads();   // vmcnt(0) drained: tile ready

        // S = Q K^T (split: qh*kh + qh*kl + ql*kh)
        f32x4 sf[4];
        #pragma unroll
        for (int kf = 0; kf < 4; ++kf) sf[kf] = (f32x4)(0.0f);
        #pragma unroll
        for (int db = 0; db < 4; ++db) {
            int kb = db * 4 + q4;
            #pragma unroll
            for (int kf = 0; kf < 4; ++kf) {
                s16x8 bh  = *(const s16x8*)&Klds[0][lswK(kf * 16 + r15, kb)];
                s16x8 bl2 = *(const s16x8*)&Klds[1][lswK(kf * 16 + r15, kb)];
                sf[kf] = MFMA16(qfh[db], bh, sf[kf]);
                sf[kf] = MFMA16(qfh[db], bl2, sf[kf]);
                sf[kf] = MFMA16(qfl[db], bh, sf[kf]);
            }
        }

        if (kt == qt) {   // diagonal mask
            #pragma unroll
            for (int kf = 0; kf < 4; ++kf) {
                int col = kf * 16 + r15;
                #pragma unroll
                for (int r = 0; r < 4; ++r) {
                    int rowg = wq * 16 + q4 * 4 + r;
                    if (col > rowg) sf[kf][r] = -1e30f;
                }
            }
        }

        // row max over 16-lane group
        float pmax[4];
        #pragma unroll
        for (int r = 0; r < 4; ++r)
            pmax[r] = fmaxf(fmaxf(sf[0][r], sf[1][r]), fmaxf(sf[2][r], sf[3][r]));
        #pragma unroll
        for (int o = 1; o < 16; o <<= 1)
            #pragma unroll
            for (int r = 0; r < 4; ++r)
                pmax[r] = fmaxf(pmax[r], __shfl_xor(pmax[r], o));

        // defer-max (T13)
        float dmax = fmaxf(fmaxf(pmax[0] - mrow[0], pmax[1] - mrow[1]),
                           fmaxf(pmax[2] - mrow[2], pmax[3] - mrow[3]));
        if (!__all(dmax <= 8.0f)) {
            #pragma unroll
            for (int r = 0; r < 4; ++r) {
                float mn = fmaxf(mrow[r], pmax[r]);
                float corr = __expf(mrow[r] - mn);
                mrow[r] = mn;
                lrow[r] *= corr;
                #pragma unroll
                for (int db = 0; db < 8; ++db) acco[db][r] *= corr;
            }
        }

        // P = exp(S - m); row-sum
        float rs[4];
        #pragma unroll
        for (int r = 0; r < 4; ++r) {
            float s0 = __expf(sf[0][r] - mrow[r]);
            float s1 = __expf(sf[1][r] - mrow[r]);
            float s2 = __expf(sf[2][r] - mrow[r]);
            float s3 = __expf(sf[3][r] - mrow[r]);
            sf[0][r] = s0; sf[1][r] = s1; sf[2][r] = s2; sf[3][r] = s3;
            rs[r] = (s0 + s1) + (s2 + s3);
        }
        #pragma unroll
        for (int o = 1; o < 16; o <<= 1)
            #pragma unroll
            for (int r = 0; r < 4; ++r)
                rs[r] += __shfl_xor(rs[r], o);
        #pragma unroll
        for (int r = 0; r < 4; ++r) lrow[r] += rs[r];

        // P -> LDS bf16 (wave-private rows; same-wave RAW)
        #pragma unroll
        for (int kf = 0; kf < 4; ++kf) {
            int col = kf * 16 + r15;
            #pragma unroll
            for (int r = 0; r < 4; ++r) {
                int prow = wq * 16 + q4 * 4 + r;
                Psh[lsw(prow, col >> 3, 8) + (col & 7)] = f2bf(sf[kf][r]);
            }
        }
        s16x8 pa0 = *(const s16x8*)&Psh[lsw(wq * 16 + r15, q4, 8)];
        s16x8 pa1 = *(const s16x8*)&Psh[lsw(wq * 16 + r15, 4 + q4, 8)];

        // O += P V
        #pragma unroll
        for (int db = 0; db < 8; ++db) {
            s16x8 vb0 = *(const s16x8*)&Vts[lsw(db * 16 + r15, q4, 8)];
            s16x8 vb1 = *(const s16x8*)&Vts[lsw(db * 16 + r15, 4 + q4, 8)];
            acco[db] = MFMA16(pa0, vb0, acco[db]);
            acco[db] = MFMA16(pa1, vb1, acco[db]);
        }

        __syncthreads();  // all waves done with this tile's LDS before restage
    }

    // epilogue: normalize, pack bf16 rows in LDS scratch, coalesced store
    u16* scr = ((u16*)Klds) + w * 2048;    // 8 waves x 4KB inside Klds (32KB)
    float inv[4];
    #pragma unroll
    for (int r = 0; r < 4; ++r) inv[r] = 1.0f / lrow[r];
    #pragma unroll
    for (int db = 0; db < 8; ++db)
        #pragma unroll
        for (int r = 0; r < 4; ++r)
            scr[(q4 * 4 + r) * 128 + db * 16 + r15] = f2bf(acco[db][r] * inv[r]);
    #pragma unroll
    for (int p = 0; p < 4; ++p) {
        int idx2 = p * 512 + lane * 8;
        int lr = idx2 >> 7, col = idx2 & 127;
        size_t grow = (size_t)qt * 64 + wq * 16 + lr;
        *(int4*)&aoh[grow * QDIM + (size_t)head * HD + col] = *(const int4*)&scr[idx2];
    }
}

// ---------------------------------------------------------------------------
extern "C" void kernel_launch(void* const* d_in, const int* in_sizes, int n_in,
                              void* d_out, int out_size, void* d_ws, size_t ws_size,
                              hipStream_t stream) {
    const float* x   = (const float*)d_in[0];
    const int*   pos = (const int*)d_in[1];
    const float* w_q = (const float*)d_in[2];
    const float* w_k = (const float*)d_in[3];
    const float* w_v = (const float*)d_in[4];
    const float* w_o = (const float*)d_in[5];

    float* out   = (float*)d_out;
    float* out_k = out + (size_t)S_LEN * DMODEL;
    float* out_v = out_k + (size_t)NKV * S_LEN * HD;

    // ---- workspace arena ----
    char* ws = (char*)d_ws;
    size_t off = 0;
    auto alloc = [&](size_t bytes) { char* p = ws + off; off += (bytes + 255) & ~255ull; return p; };
    float* cost = (float*)alloc((size_t)S_LEN * 64 * 4);
    float* sint = (float*)alloc((size_t)S_LEN * 64 * 4);
    float* Q32  = (float*)alloc((size_t)S_LEN * QDIM * 4);      // later: AOH (bf16)
    u16* XH  = (u16*)alloc((size_t)S_LEN * DMODEL * 2);         // later: KH
    u16* XL  = (u16*)alloc((size_t)S_LEN * DMODEL * 2);         // later: KL
    u16* WQH = (u16*)alloc((size_t)QDIM * DMODEL * 2);
    u16* WQL = (u16*)alloc((size_t)QDIM * DMODEL * 2);          // later: QH
    u16* WKH = (u16*)alloc((size_t)KVDIM * DMODEL * 2);
    u16* WKL = (u16*)alloc((size_t)KVDIM * DMODEL * 2);
    u16* WVH = (u16*)alloc((size_t)KVDIM * DMODEL * 2);
    u16* WOH = (u16*)alloc((size_t)DMODEL * QDIM * 2);
    u16* QL  = (u16*)alloc((size_t)S_LEN * QDIM * 2);
    u16* VT  = (u16*)alloc((size_t)NKV * HD * S_LEN * 2);
    u16* AOH = (u16*)Q32;     // alias: Q32 dead after rope_qk_split
    u16* KH  = XH;            // alias: XH dead after gemm_qkv2
    u16* KL  = XL;
    u16* QH  = WQL;           // alias: WQL dead after gemm_qkv2

    // 1. all input prep (splits + rope tables) in one launch
    prep_all<<<PREP_TOTAL / 256, 256, 0, stream>>>(
        x, w_q, w_k, w_v, w_o, pos, XH, XL, WQH, WQL, WKH, WKL, WVH, WOH, cost, sint);

    // 2. fused Q/K/V projections (segmented plain-bf16)
    gemm_qkv2<<<dim3(48, 16), 256, 0, stream>>>(
        XH, XL, WQH, WQL, WKH, WKL, WVH, Q32, out_k, out_v);

    // 3. V^T + fused rope/scale/split for q and k
    vt_transpose<<<dim3(64, 8), 256, 0, stream>>>(out_v, VT);
    rope_qk_split<<<(S_LEN * (NH + NKV) * 64) / 256, 256, 0, stream>>>(
        Q32, out_k, cost, sint, QH, QL, KH, KL);

    // 4. attention -> bf16 AO
    attn_mfma6<<<512, 512, 0, stream>>>(QH, QL, KH, KL, VT, AOH);

    // 5. O projection (plain bf16)
    gemm_o2<<<dim3(DMODEL / 128, 16), 256, 0, stream>>>(AOH, WOH, out);
}

// Round 8
// 467.901 us; speedup vs baseline: 1.1077x; 1.0381x over previous
//
#include <hip/hip_runtime.h>
#include <math.h>

#define S_LEN 2048
#define DMODEL 2560
#define NH 32
#define NKV 8
#define HD 128
#define QDIM (NH*HD)     // 4096
#define KVDIM (NKV*HD)   // 1024
#define ROPE_THETA 5000000.0
#define QK_SCALE 0.08838834764831843f

typedef __attribute__((ext_vector_type(8))) short s16x8;
typedef __attribute__((ext_vector_type(4))) float f32x4;
typedef unsigned short u16;

#define MFMA16(a,b,c) __builtin_amdgcn_mfma_f32_16x16x32_bf16((a),(b),(c),0,0,0)

__device__ __forceinline__ u16 f2bf(float x) {
    union { float f; unsigned u; } v; v.f = x;
    unsigned r = v.u + 0x7FFFu + ((v.u >> 16) & 1u);
    return (u16)(r >> 16);
}
__device__ __forceinline__ float bf2f(u16 h) {
    union { unsigned u; float f; } v; v.u = ((unsigned)h) << 16;
    return v.f;
}

// Swizzled LDS index, CKU units of 8 bf16 per row; XOR low-3 bits of unit.
__device__ __forceinline__ int lsw(int row, int kb, int CKU) {
    return (((row * CKU + kb) ^ (row & 7)) << 3);
}
// K arrays: CKU=16, XOR all 4 unit bits (full 256B spread).
__device__ __forceinline__ int lswK(int row, int kb) {
    return ((row * 16 + (kb ^ (row & 15))) << 3);
}

// async global->LDS, 16B per lane; LDS dest = wave-uniform base + lane*16.
__device__ __forceinline__ void gload16(const void* g, void* l) {
    __builtin_amdgcn_global_load_lds(
        (const __attribute__((address_space(1))) void*)g,
        (__attribute__((address_space(3))) void*)l, 16, 0, 0);
}

// ---------------------------------------------------------------------------
// prep_all: all input-side elementwise work in ONE launch.
// ---------------------------------------------------------------------------
#define N4_X   (S_LEN*DMODEL/4)      // 1310720
#define N4_WQ  (QDIM*DMODEL/4)       // 2621440
#define N4_WKV (KVDIM*DMODEL/4)      // 655360
#define N4_WO  (DMODEL*QDIM/4)       // 2621440
#define N_TAB  (S_LEN*64)            // 131072
#define PREP_TOTAL (N4_X + N4_WQ + N4_WKV + N4_WKV + N4_WO + N_TAB)

__device__ __forceinline__ void split4(const float* in, long i,
                                       u16* hi, u16* lo) {
    float4 v = ((const float4*)in)[i];
    float a[4] = {v.x, v.y, v.z, v.w};
    u16 hh[4], ll[4];
    #pragma unroll
    for (int j = 0; j < 4; ++j) {
        hh[j] = f2bf(a[j]);
        ll[j] = f2bf(a[j] - bf2f(hh[j]));
    }
    ((uint2*)hi)[i] = make_uint2((unsigned)hh[0] | ((unsigned)hh[1] << 16),
                                 (unsigned)hh[2] | ((unsigned)hh[3] << 16));
    ((uint2*)lo)[i] = make_uint2((unsigned)ll[0] | ((unsigned)ll[1] << 16),
                                 (unsigned)ll[2] | ((unsigned)ll[3] << 16));
}
__device__ __forceinline__ void cvt4(const float* in, long i, u16* out) {
    float4 v = ((const float4*)in)[i];
    u16 h0 = f2bf(v.x), h1 = f2bf(v.y), h2 = f2bf(v.z), h3 = f2bf(v.w);
    ((uint2*)out)[i] = make_uint2((unsigned)h0 | ((unsigned)h1 << 16),
                                  (unsigned)h2 | ((unsigned)h3 << 16));
}

__global__ __launch_bounds__(256)
void prep_all(const float* __restrict__ x, const float* __restrict__ w_q,
              const float* __restrict__ w_k, const float* __restrict__ w_v,
              const float* __restrict__ w_o, const int* __restrict__ pos,
              u16* __restrict__ XH, u16* __restrict__ XL,
              u16* __restrict__ WQH, u16* __restrict__ WQL,
              u16* __restrict__ WKH, u16* __restrict__ WKL,
              u16* __restrict__ WVH, u16* __restrict__ WOH,
              float* __restrict__ cost, float* __restrict__ sint) {
    long i = (long)blockIdx.x * 256 + threadIdx.x;
    if (i < N4_X) { split4(x, i, XH, XL); return; }
    i -= N4_X;
    if (i < N4_WQ) { split4(w_q, i, WQH, WQL); return; }
    i -= N4_WQ;
    if (i < N4_WKV) { split4(w_k, i, WKH, WKL); return; }
    i -= N4_WKV;
    if (i < N4_WKV) { cvt4(w_v, i, WVH); return; }
    i -= N4_WKV;
    if (i < N4_WO) { cvt4(w_o, i, WOH); return; }
    i -= N4_WO;
    if (i < N_TAB) {
        int s = (int)(i >> 6), j = (int)(i & 63);
        double inv = pow((double)ROPE_THETA, -(double)j / 64.0);
        double ang = (double)pos[s] * inv;
        cost[i] = (float)cos(ang);
        sint[i] = (float)sin(ang);
    }
}

// ---------------------------------------------------------------------------
// merged rope: q (scaled, ws) + k (in-place fp32 cache) -> bf16 hi/lo splits
// ---------------------------------------------------------------------------
__global__ __launch_bounds__(256)
void rope_qk_split(float* __restrict__ q32, float* __restrict__ k,
                   const float* __restrict__ cost, const float* __restrict__ sint,
                   u16* __restrict__ qhh, u16* __restrict__ qll,
                   u16* __restrict__ khh, u16* __restrict__ kll) {
    int idx = blockIdx.x * 256 + threadIdx.x;
    if (idx < S_LEN * NH * 64) {
        int j = idx & 63;
        int h = (idx >> 6) & 31;
        int s = idx >> 11;
        float c = cost[(s << 6) + j], sn = sint[(s << 6) + j];
        size_t base = (size_t)s * QDIM + (size_t)h * HD;
        float x1 = q32[base + j], x2 = q32[base + 64 + j];
        float y1 = (x1 * c - x2 * sn) * QK_SCALE;
        float y2 = (x2 * c + x1 * sn) * QK_SCALE;
        u16 h1 = f2bf(y1), h2 = f2bf(y2);
        qhh[base + j] = h1;      qll[base + j] = f2bf(y1 - bf2f(h1));
        qhh[base + 64 + j] = h2; qll[base + 64 + j] = f2bf(y2 - bf2f(h2));
    } else {
        idx -= S_LEN * NH * 64;
        int j = idx & 63;
        int s = (idx >> 6) & 2047;
        int h = idx >> 17;
        float c = cost[(s << 6) + j], sn = sint[(s << 6) + j];
        size_t base = ((size_t)h * S_LEN + s) * HD;
        float x1 = k[base + j], x2 = k[base + 64 + j];
        float y1 = x1 * c - x2 * sn;
        float y2 = x2 * c + x1 * sn;
        k[base + j] = y1; k[base + 64 + j] = y2;
        u16 h1 = f2bf(y1), h2 = f2bf(y2);
        khh[base + j] = h1;      kll[base + j] = f2bf(y1 - bf2f(h1));
        khh[base + 64 + j] = h2; kll[base + 64 + j] = f2bf(y2 - bf2f(h2));
    }
}

// ---------------------------------------------------------------------------
// V^T builder: v [8][2048][128] fp32 -> vt [8][128][2048] bf16 (coalesced).
// ---------------------------------------------------------------------------
__global__ __launch_bounds__(256)
void vt_transpose(const float* __restrict__ v, u16* __restrict__ vt) {
    __shared__ u16 t[64][80];
    const int kvh = blockIdx.y;
    const int st = blockIdx.x >> 1, dt = blockIdx.x & 1;
    const int tid = threadIdx.x;
    const int r = tid & 15, c4 = (tid >> 4) * 4;
    const float* vb = v + ((size_t)kvh * S_LEN + st * 64) * HD + dt * 64;
    #pragma unroll
    for (int p = 0; p < 4; ++p) {
        int row = p * 16 + r;
        float4 x = *(const float4*)&vb[(size_t)row * HD + c4];
        t[c4 + 0][row] = f2bf(x.x);
        t[c4 + 1][row] = f2bf(x.y);
        t[c4 + 2][row] = f2bf(x.z);
        t[c4 + 3][row] = f2bf(x.w);
    }
    __syncthreads();
    #pragma unroll
    for (int p = 0; p < 2; ++p) {
        int idx = p * 256 + tid;
        int dr = idx >> 3, sc = idx & 7;
        size_t o = ((size_t)kvh * HD + dt * 64 + dr) * S_LEN + st * 64 + sc * 8;
        *(int4*)&vt[o] = *(const int4*)&t[dr][sc * 8];
    }
}

// ---------------------------------------------------------------------------
// Segmented plain-bf16 MFMA GEMM (NT). 128x128, BK=64, 32KB LDS.
// ---------------------------------------------------------------------------
__device__ __forceinline__ void gemm_seg_body(
    u16* lds, const u16* __restrict__ a0, const u16* __restrict__ a1,
    const u16* __restrict__ a2, const u16* __restrict__ b0,
    const u16* __restrict__ b1, const u16* __restrict__ b2,
    float* __restrict__ C, int N, int Kb, int nseg, int m0, int n0, int cmode) {
    u16* As = lds;
    u16* Bs = lds + 8192;
    const int tid = threadIdx.x;
    const int lane = tid & 63, w = tid >> 6;
    const int q4 = lane >> 4, r15 = lane & 15;
    const int wm = (w >> 1) * 64, wn = (w & 1) * 64;

    f32x4 acc[4][4];
    #pragma unroll
    for (int i = 0; i < 4; ++i)
        #pragma unroll
        for (int j = 0; j < 4; ++j) acc[i][j] = (f32x4)(0.0f);

    const int KT = nseg * Kb;
    for (int k0 = 0; k0 < KT; k0 += 64) {
        const int si = (k0 >= 2 * Kb) ? 2 : ((k0 >= Kb) ? 1 : 0);
        const int koff = k0 - si * Kb;
        const u16* Ag = (si == 0) ? a0 : ((si == 1) ? a1 : a2);
        const u16* Bg = (si == 0) ? b0 : ((si == 1) ? b1 : b2);
        __syncthreads();
        for (int ch = w; ch < 16; ch += 4) {
            int u = ch * 64 + lane;
            int row = u >> 3;
            int kb = (u & 7) ^ (row & 7);
            size_t go = (size_t)row * Kb + koff + kb * 8;
            gload16(Ag + (size_t)m0 * Kb + go, &As[ch * 512]);
            gload16(Bg + (size_t)n0 * Kb + go, &Bs[ch * 512]);
        }
        __syncthreads();   // drains vmcnt(0): LDS tiles ready

        #pragma unroll
        for (int kh2 = 0; kh2 < 2; ++kh2) {
            int kb = kh2 * 4 + q4;
            s16x8 ah[4], bh[4];
            #pragma unroll
            for (int i = 0; i < 4; ++i) ah[i] = *(const s16x8*)&As[lsw(wm + i * 16 + r15, kb, 8)];
            #pragma unroll
            for (int j = 0; j < 4; ++j) bh[j] = *(const s16x8*)&Bs[lsw(wn + j * 16 + r15, kb, 8)];
            #pragma unroll
            for (int i = 0; i < 4; ++i)
                #pragma unroll
                for (int j = 0; j < 4; ++j)
                    acc[i][j] = MFMA16(ah[i], bh[j], acc[i][j]);
        }
    }

    // epilogue: D layout col = lane&15, row = (lane>>4)*4 + r
    #pragma unroll
    for (int i = 0; i < 4; ++i) {
        #pragma unroll
        for (int j = 0; j < 4; ++j) {
            int col = n0 + wn + j * 16 + r15;
            #pragma unroll
            for (int r = 0; r < 4; ++r) {
                int row = m0 + wm + i * 16 + q4 * 4 + r;
                float val = acc[i][j][r];
                if (cmode == 0)
                    C[(size_t)row * N + col] = val;
                else
                    C[((size_t)(col >> 7) * S_LEN + row) * HD + (col & 127)] = val;
            }
        }
    }
}

// fused Q/K/V projection: 1-D grid 768, XCD-chunked swizzle (T1).
__global__ __launch_bounds__(256)
void gemm_qkv2(const u16* __restrict__ XH, const u16* __restrict__ XL,
               const u16* __restrict__ WQH, const u16* __restrict__ WQL,
               const u16* __restrict__ WKH, const u16* __restrict__ WKL,
               const u16* __restrict__ WVH,
               float* __restrict__ Q32, float* __restrict__ out_k,
               float* __restrict__ out_v) {
    __shared__ u16 lds[16384];
    const int bid = blockIdx.x;                       // 768 = 8 XCD x 96
    const int orig = (bid & 7) * 96 + (bid >> 3);     // contiguous chunk per XCD
    const int bx = orig % 48, m0 = (orig / 48) * 128;
    if (bx < 32)        // Q: xh.wqh + xh.wql + xl.wqh
        gemm_seg_body(lds, XH, XH, XL, WQH, WQL, WQH, Q32, QDIM, DMODEL, 3, m0, bx * 128, 0);
    else if (bx < 40)   // K: split-3
        gemm_seg_body(lds, XH, XH, XL, WKH, WKL, WKH, out_k, KVDIM, DMODEL, 3, m0, (bx - 32) * 128, 1);
    else                // V: single-term
        gemm_seg_body(lds, XH, XH, XL, WVH, WVH, WVH, out_v, KVDIM, DMODEL, 1, m0, (bx - 40) * 128, 1);
}

// O projection (plain bf16): 1-D grid 320, XCD-chunked swizzle.
__global__ __launch_bounds__(256)
void gemm_o2(const u16* __restrict__ AOH, const u16* __restrict__ WOH,
             float* __restrict__ out) {
    __shared__ u16 lds[16384];
    const int bid = blockIdx.x;                       // 320 = 8 XCD x 40
    const int orig = (bid & 7) * 40 + (bid >> 3);
    const int bx = orig % 20, m0 = (orig / 20) * 128;
    gemm_seg_body(lds, AOH, AOH, AOH, WOH, WOH, WOH, out, DMODEL, QDIM, 1,
                  m0, bx * 128, 0);
}

// ---------------------------------------------------------------------------
// MFMA flash attention v7 = v6 (one q-tile/block, low regs) + double-buffered
// K/V staging (T3-minimum 2-phase: stage(t+1) issued BEFORE compute(t); one
// drain+barrier per tile). LDS 112KB -> 1 block/CU, 8 waves.
// Grid 512: bid&7 = kvh (XCD-pinned); complement qt mapping balances the two
// sequential blocks per CU (qt sums to 31).
// ---------------------------------------------------------------------------
__global__ __launch_bounds__(512, 2)
void attn_mfma7(const u16* __restrict__ qh, const u16* __restrict__ ql,
                const u16* __restrict__ kh, const u16* __restrict__ kl,
                const u16* __restrict__ vt, u16* __restrict__ aoh) {
    const int bid = blockIdx.x;
    const int kvh = bid & 7;
    const int rest = bid >> 3;             // 0..63
    const int hp = rest & 1;
    const int idx = rest >> 1;             // 0..31
    const int qt = (idx < 16) ? idx : 47 - idx;

    const int tid = threadIdx.x, lane = tid & 63, w = tid >> 6;
    const int lh = w >> 2, wq = w & 3;
    const int head = kvh * 4 + hp * 2 + lh;
    const int q4 = lane >> 4, r15 = lane & 15;

    __shared__ u16 Khs[2][64 * 128];       // 32KB (also epilogue scratch)
    __shared__ u16 Kls[2][64 * 128];       // 32KB
    __shared__ u16 Vts[2][128 * 64];       // 32KB
    __shared__ u16 Ps[2][64 * 64];         // 16KB
    u16* Psh = Ps[lh];

    // Q fragments in registers
    s16x8 qfh[4], qfl[4];
    {
        size_t qrow = (size_t)qt * 64 + wq * 16 + r15;
        const u16* qb  = qh + qrow * QDIM + (size_t)head * HD + q4 * 8;
        const u16* qb2 = ql + qrow * QDIM + (size_t)head * HD + q4 * 8;
        #pragma unroll
        for (int db = 0; db < 4; ++db) {
            qfh[db] = *(const s16x8*)(qb + db * 32);
            qfl[db] = *(const s16x8*)(qb2 + db * 32);
        }
    }

    f32x4 acco[8];
    #pragma unroll
    for (int db = 0; db < 8; ++db) acco[db] = (f32x4)(0.0f);
    float mrow[4] = {-1e30f, -1e30f, -1e30f, -1e30f};
    float lrow[4] = {0.f, 0.f, 0.f, 0.f};

    const u16* kbase = kh + (size_t)kvh * S_LEN * HD;
    const u16* lbase = kl + (size_t)kvh * S_LEN * HD;
    const u16* vbase = vt + (size_t)kvh * HD * S_LEN;

    auto stage = [&](int kt, int buf) {
        for (int c = w; c < 48; c += 8) {
            int c15 = c & 15;
            int u = c15 * 64 + lane;
            if (c < 32) {
                int krow = u >> 4;
                int kb = (u & 15) ^ (krow & 15);
                size_t g = (size_t)(kt * 64 + krow) * HD + kb * 8;
                const u16* src = (c < 16 ? kbase : lbase) + g;
                u16* dst = (c < 16 ? &Khs[buf][c15 * 512] : &Kls[buf][c15 * 512]);
                gload16(src, dst);
            } else {
                int vrow = u >> 3;
                int vb2 = (u & 7) ^ (vrow & 7);
                gload16(vbase + (size_t)vrow * S_LEN + kt * 64 + vb2 * 8,
                        &Vts[buf][c15 * 512]);
            }
        }
    };

    stage(0, 0);
    __syncthreads();   // prologue drain: tile 0 resident

    int cur = 0;
    for (int kt = 0; kt <= qt; ++kt) {
        if (kt < qt) stage(kt + 1, cur ^ 1);   // prefetch: in flight during compute

        // S = Q K^T (split: qh*kh + qh*kl + ql*kh)
        f32x4 sf[4];
        #pragma unroll
        for (int kf = 0; kf < 4; ++kf) sf[kf] = (f32x4)(0.0f);
        #pragma unroll
        for (int db = 0; db < 4; ++db) {
            int kb = db * 4 + q4;
            #pragma unroll
            for (int kf = 0; kf < 4; ++kf) {
                s16x8 bh  = *(const s16x8*)&Khs[cur][lswK(kf * 16 + r15, kb)];
                s16x8 bl2 = *(const s16x8*)&Kls[cur][lswK(kf * 16 + r15, kb)];
                sf[kf] = MFMA16(qfh[db], bh, sf[kf]);
                sf[kf] = MFMA16(qfh[db], bl2, sf[kf]);
                sf[kf] = MFMA16(qfl[db], bh, sf[kf]);
            }
        }

        if (kt == qt) {   // diagonal mask
            #pragma unroll
            for (int kf = 0; kf < 4; ++kf) {
                int col = kf * 16 + r15;
                #pragma unroll
                for (int r = 0; r < 4; ++r) {
                    int rowg = wq * 16 + q4 * 4 + r;
                    if (col > rowg) sf[kf][r] = -1e30f;
                }
            }
        }

        // row max over 16-lane group
        float pmax[4];
        #pragma unroll
        for (int r = 0; r < 4; ++r)
            pmax[r] = fmaxf(fmaxf(sf[0][r], sf[1][r]), fmaxf(sf[2][r], sf[3][r]));
        #pragma unroll
        for (int o = 1; o < 16; o <<= 1)
            #pragma unroll
            for (int r = 0; r < 4; ++r)
                pmax[r] = fmaxf(pmax[r], __shfl_xor(pmax[r], o));

        // defer-max (T13)
        float dmax = fmaxf(fmaxf(pmax[0] - mrow[0], pmax[1] - mrow[1]),
                           fmaxf(pmax[2] - mrow[2], pmax[3] - mrow[3]));
        if (!__all(dmax <= 8.0f)) {
            #pragma unroll
            for (int r = 0; r < 4; ++r) {
                float mn = fmaxf(mrow[r], pmax[r]);
                float corr = __expf(mrow[r] - mn);
                mrow[r] = mn;
                lrow[r] *= corr;
                #pragma unroll
                for (int db = 0; db < 8; ++db) acco[db][r] *= corr;
            }
        }

        // P = exp(S - m); row-sum
        float rs[4];
        #pragma unroll
        for (int r = 0; r < 4; ++r) {
            float s0 = __expf(sf[0][r] - mrow[r]);
            float s1 = __expf(sf[1][r] - mrow[r]);
            float s2 = __expf(sf[2][r] - mrow[r]);
            float s3 = __expf(sf[3][r] - mrow[r]);
            sf[0][r] = s0; sf[1][r] = s1; sf[2][r] = s2; sf[3][r] = s3;
            rs[r] = (s0 + s1) + (s2 + s3);
        }
        #pragma unroll
        for (int o = 1; o < 16; o <<= 1)
            #pragma unroll
            for (int r = 0; r < 4; ++r)
                rs[r] += __shfl_xor(rs[r], o);
        #pragma unroll
        for (int r = 0; r < 4; ++r) lrow[r] += rs[r];

        // P -> LDS bf16 (wave-private rows; same-wave RAW)
        #pragma unroll
        for (int kf = 0; kf < 4; ++kf) {
            int col = kf * 16 + r15;
            #pragma unroll
            for (int r = 0; r < 4; ++r) {
                int prow = wq * 16 + q4 * 4 + r;
                Psh[lsw(prow, col >> 3, 8) + (col & 7)] = f2bf(sf[kf][r]);
            }
        }
        s16x8 pa0 = *(const s16x8*)&Psh[lsw(wq * 16 + r15, q4, 8)];
        s16x8 pa1 = *(const s16x8*)&Psh[lsw(wq * 16 + r15, 4 + q4, 8)];

        // O += P V
        #pragma unroll
        for (int db = 0; db < 8; ++db) {
            s16x8 vb0 = *(const s16x8*)&Vts[cur][lsw(db * 16 + r15, q4, 8)];
            s16x8 vb1 = *(const s16x8*)&Vts[cur][lsw(db * 16 + r15, 4 + q4, 8)];
            acco[db] = MFMA16(pa0, vb0, acco[db]);
            acco[db] = MFMA16(pa1, vb1, acco[db]);
        }

        __syncthreads();  // drain vmcnt (tile t+1 landed) + all waves done with cur
        cur ^= 1;
    }

    // epilogue: normalize, pack bf16 rows in LDS scratch, coalesced store
    u16* scr = ((u16*)Khs) + w * 2048;    // 8 waves x 4KB spanning Khs (32KB)
    float inv[4];
    #pragma unroll
    for (int r = 0; r < 4; ++r) inv[r] = 1.0f / lrow[r];
    #pragma unroll
    for (int db = 0; db < 8; ++db)
        #pragma unroll
        for (int r = 0; r < 4; ++r)
            scr[(q4 * 4 + r) * 128 + db * 16 + r15] = f2bf(acco[db][r] * inv[r]);
    #pragma unroll
    for (int p = 0; p < 4; ++p) {
        int idx2 = p * 512 + lane * 8;
        int lr = idx2 >> 7, col = idx2 & 127;
        size_t grow = (size_t)qt * 64 + wq * 16 + lr;
        *(int4*)&aoh[grow * QDIM + (size_t)head * HD + col] = *(const int4*)&scr[idx2];
    }
}

// ---------------------------------------------------------------------------
extern "C" void kernel_launch(void* const* d_in, const int* in_sizes, int n_in,
                              void* d_out, int out_size, void* d_ws, size_t ws_size,
                              hipStream_t stream) {
    const float* x   = (const float*)d_in[0];
    const int*   pos = (const int*)d_in[1];
    const float* w_q = (const float*)d_in[2];
    const float* w_k = (const float*)d_in[3];
    const float* w_v = (const float*)d_in[4];
    const float* w_o = (const float*)d_in[5];

    float* out   = (float*)d_out;
    float* out_k = out + (size_t)S_LEN * DMODEL;
    float* out_v = out_k + (size_t)NKV * S_LEN * HD;

    // ---- workspace arena ----
    char* ws = (char*)d_ws;
    size_t off = 0;
    auto alloc = [&](size_t bytes) { char* p = ws + off; off += (bytes + 255) & ~255ull; return p; };
    float* cost = (float*)alloc((size_t)S_LEN * 64 * 4);
    float* sint = (float*)alloc((size_t)S_LEN * 64 * 4);
    float* Q32  = (float*)alloc((size_t)S_LEN * QDIM * 4);      // later: AOH (bf16)
    u16* XH  = (u16*)alloc((size_t)S_LEN * DMODEL * 2);         // later: KH
    u16* XL  = (u16*)alloc((size_t)S_LEN * DMODEL * 2);         // later: KL
    u16* WQH = (u16*)alloc((size_t)QDIM * DMODEL * 2);
    u16* WQL = (u16*)alloc((size_t)QDIM * DMODEL * 2);          // later: QH
    u16* WKH = (u16*)alloc((size_t)KVDIM * DMODEL * 2);
    u16* WKL = (u16*)alloc((size_t)KVDIM * DMODEL * 2);
    u16* WVH = (u16*)alloc((size_t)KVDIM * DMODEL * 2);
    u16* WOH = (u16*)alloc((size_t)DMODEL * QDIM * 2);
    u16* QL  = (u16*)alloc((size_t)S_LEN * QDIM * 2);
    u16* VT  = (u16*)alloc((size_t)NKV * HD * S_LEN * 2);
    u16* AOH = (u16*)Q32;     // alias: Q32 dead after rope_qk_split
    u16* KH  = XH;            // alias: XH dead after gemm_qkv2
    u16* KL  = XL;
    u16* QH  = WQL;           // alias: WQL dead after gemm_qkv2

    // 1. all input prep (splits + rope tables) in one launch
    prep_all<<<PREP_TOTAL / 256, 256, 0, stream>>>(
        x, w_q, w_k, w_v, w_o, pos, XH, XL, WQH, WQL, WKH, WKL, WVH, WOH, cost, sint);

    // 2. fused Q/K/V projections (segmented plain-bf16, XCD-swizzled)
    gemm_qkv2<<<768, 256, 0, stream>>>(
        XH, XL, WQH, WQL, WKH, WKL, WVH, Q32, out_k, out_v);

    // 3. V^T + fused rope/scale/split for q and k
    vt_transpose<<<dim3(64, 8), 256, 0, stream>>>(out_v, VT);
    rope_qk_split<<<(S_LEN * (NH + NKV) * 64) / 256, 256, 0, stream>>>(
        Q32, out_k, cost, sint, QH, QL, KH, KL);

    // 4. attention -> bf16 AO
    attn_mfma7<<<512, 512, 0, stream>>>(QH, QL, KH, KL, VT, AOH);

    // 5. O projection (plain bf16, XCD-swizzled)
    gemm_o2<<<320, 256, 0, stream>>>(AOH, WOH, out);
}